// Round 6
// baseline (580.410 us; speedup 1.0000x reference)
//
#include <hip/hip_runtime.h>
#include <hip/hip_bf16.h>
#include <math.h>

#define B 2048
#define L 100
#define D 256

typedef _Float16 half8 __attribute__((ext_vector_type(8)));
typedef __attribute__((ext_vector_type(4))) float f32x4;

// ---------------------------------------------------------------------------
// K0: abs_w[t] = abs_embed[t]·w_abs, relw[i] = rel_embed[i]·w_rel,
//     exclusive scan of doc_lens.
// ---------------------------------------------------------------------------
__global__ __launch_bounds__(256) void k0_precompute(
    const float* __restrict__ abs_embed, const float* __restrict__ w_abs,
    const float* __restrict__ rel_embed, const float* __restrict__ w_rel,
    const int* __restrict__ dls,
    float* __restrict__ abs_w, float* __restrict__ relw, int* __restrict__ offs)
{
    int t = threadIdx.x;
    if (t < 100) {
        float s = 0.f;
        for (int j = 0; j < 50; j++) s += abs_embed[t * 50 + j] * w_abs[j];
        abs_w[t] = s;
    }
    if (t < 25) {
        float s = 0.f;
        for (int j = 0; j < 50; j++) s += rel_embed[t * 50 + j] * w_rel[j];
        relw[t] = s;
    }
    __shared__ int lds[256];
    int loc[8];
    int sum = 0;
    for (int k = 0; k < 8; k++) { loc[k] = sum; sum += dls[t * 8 + k]; }
    lds[t] = sum;
    __syncthreads();
    for (int off = 1; off < 256; off <<= 1) {
        int v = (t >= off) ? lds[t - off] : 0;
        __syncthreads();
        lds[t] += v;
        __syncthreads();
    }
    int base = (t > 0) ? lds[t - 1] : 0;
    for (int k = 0; k < 8; k++) offs[t * 8 + k] = base + loc[k];
}

// ---------------------------------------------------------------------------
// K0b: split-fp16 transpose of W_nov: Wh/Wl are [N][K] fp16,
//      W = Wh + Wl with |err| <= 2^-22 rel.  (2 x 128 KB, L2-resident)
// ---------------------------------------------------------------------------
__global__ __launch_bounds__(256) void k0b_wt(
    const float* __restrict__ W, _Float16* __restrict__ Wh, _Float16* __restrict__ Wl)
{
    int n = blockIdx.x, k = threadIdx.x;
    float w = W[k * D + n];
    _Float16 hi = (_Float16)w;
    _Float16 lo = (_Float16)(w - (float)hi);
    Wh[n * D + k] = hi;
    Wl[n * D + k] = lo;
}

// ---------------------------------------------------------------------------
// K1: docs[b,d] = sum_{t<dl} sent[b,t,d] / dl
//     One WAVE per doc; 4-row unrolled so 4 independent 1 KB loads are in
//     flight per latency exposure.
// ---------------------------------------------------------------------------
__global__ __launch_bounds__(256) void k1_docavg(
    const float* __restrict__ sent, const int* __restrict__ dls,
    float* __restrict__ docs)
{
    int wave = threadIdx.x >> 6;
    int lane = threadIdx.x & 63;
    int b = blockIdx.x * 4 + wave;
    int dl = dls[b];
    const float4* p = (const float4*)(sent + (size_t)b * L * D) + lane;
    float4 s = make_float4(0.f, 0.f, 0.f, 0.f);
    int t = 0;
    for (; t + 4 <= dl; t += 4) {
        float4 a = p[(size_t)t * (D / 4)];
        float4 c = p[(size_t)(t + 1) * (D / 4)];
        float4 e = p[(size_t)(t + 2) * (D / 4)];
        float4 f = p[(size_t)(t + 3) * (D / 4)];
        s.x += (a.x + c.x) + (e.x + f.x);
        s.y += (a.y + c.y) + (e.y + f.y);
        s.z += (a.z + c.z) + (e.z + f.z);
        s.w += (a.w + c.w) + (e.w + f.w);
    }
    for (; t < dl; t++) {
        float4 a = p[(size_t)t * (D / 4)];
        s.x += a.x; s.y += a.y; s.z += a.z; s.w += a.w;
    }
    float inv = 1.0f / (float)dl;
    float4 r = make_float4(s.x * inv, s.y * inv, s.z * inv, s.w * inv);
    ((float4*)(docs + (size_t)b * D))[lane] = r;
}

// ---------------------------------------------------------------------------
// K2: doc = tanh(docs @ fc_w.T + fc_b); uw = W_sal @ doc + w_content
// ---------------------------------------------------------------------------
__global__ __launch_bounds__(256) void k2_docrep(
    const float* __restrict__ docs, const float* __restrict__ fc_w,
    const float* __restrict__ fc_b, const float* __restrict__ W_sal,
    const float* __restrict__ w_content, float* __restrict__ uw)
{
    __shared__ float sd[8][D];
    __shared__ float sdoc[8][D];
    int g = blockIdx.x;
    int i = threadIdx.x;

    for (int dd = 0; dd < 8; dd++) sd[dd][i] = docs[(size_t)(g * 8 + dd) * D + i];
    __syncthreads();

    float acc[8];
    float fb = fc_b[i];
#pragma unroll
    for (int dd = 0; dd < 8; dd++) acc[dd] = fb;
    const float4* wr = (const float4*)(fc_w + (size_t)i * D);
    for (int j = 0; j < D / 4; j++) {
        float4 w = wr[j];
#pragma unroll
        for (int dd = 0; dd < 8; dd++) {
            float4 v = ((const float4*)sd[dd])[j];
            acc[dd] += w.x * v.x + w.y * v.y + w.z * v.z + w.w * v.w;
        }
    }
#pragma unroll
    for (int dd = 0; dd < 8; dd++) sdoc[dd][i] = tanhf(acc[dd]);
    __syncthreads();

    float acc2[8];
#pragma unroll
    for (int dd = 0; dd < 8; dd++) acc2[dd] = 0.f;
    const float4* wsr = (const float4*)(W_sal + (size_t)i * D);
    for (int j = 0; j < D / 4; j++) {
        float4 w = wsr[j];
#pragma unroll
        for (int dd = 0; dd < 8; dd++) {
            float4 v = ((const float4*)sdoc[dd])[j];
            acc2[dd] += w.x * v.x + w.y * v.y + w.z * v.z + w.w * v.w;
        }
    }
    float wc = w_content[i];
#pragma unroll
    for (int dd = 0; dd < 8; dd++)
        uw[(size_t)(g * 8 + dd) * D + i] = acc2[dd] + wc;
}

// ---------------------------------------------------------------------------
// K3: G(fp32) = sent @ W_nov via split-fp16 MFMA (hi*hi + hi*lo + lo*hi).
//     BK=32, double-buffered 2x16 KB LDS -> 3 blocks/CU (launch_bounds 256,3).
//     A staged fp32 via global_load_lds w16, XOR-swizzled 16B granules
//     (slot u holds global chunk u^(r&7); linear dest + pre-swizzled source
//     + swizzled read).  Counted vmcnt(4): next window's 4 stage-DMAs stay
//     in flight across compute.  fp32->fp16 split at fragment read.
//     k-granule accumulation order identical to prior rounds -> bit-identical
//     G.  No function-scope macros: lambdas + fully-unrolled w loop.
//     Grid split in two dispatches (y0) to expose other kernels in top-5.
// ---------------------------------------------------------------------------
__global__ __launch_bounds__(256, 3) void k3_mfma(
    const float* __restrict__ A, const _Float16* __restrict__ Wh,
    const _Float16* __restrict__ Wl, float* __restrict__ G, int y0)
{
    __shared__ __align__(16) float As[2][128 * 32];   // 2 x 16 KB

    int tid = threadIdx.x;
    int lane = tid & 63;
    int wv = tid >> 6;
    int n0 = blockIdx.x * 128;           // gridDim.x = 2
    int m0 = (blockIdx.y + y0) * 128;
    int m_off = (wv & 1) * 64;
    int n_off = (wv >> 1) * 64;
    int quad = lane >> 4;
    int l15 = lane & 15;

    f32x4 acc[4][4];
#pragma unroll
    for (int fi = 0; fi < 4; fi++)
#pragma unroll
        for (int fj = 0; fj < 4; fj++) acc[fi][fj] = (f32x4){0.f, 0.f, 0.f, 0.f};

    half8 bh[4], bl[4];

    // Stage K-window w (floats w*32..w*32+31) into LDS buffer (w&1).
    // Granule g = i*256 + wv*64 + lane: row r = g>>3, slot u = g&7 holds
    // global chunk u^(r&7).  Dest is wave-uniform base (+lane*16 implicit).
    auto stage = [&](int w) {
#pragma unroll
        for (int i = 0; i < 4; i++) {
            int flat = i * 256 + tid;
            int r = flat >> 3, u = flat & 7;
            int us = u ^ (r & 7);
            const float* src = A + (size_t)(m0 + r) * D + w * 32 + us * 4;
            float* dst = &As[w & 1][(i * 256 + wv * 64) * 4];
            __builtin_amdgcn_global_load_lds(
                (const __attribute__((address_space(1))) void*)src,
                (__attribute__((address_space(3))) void*)dst, 16, 0, 0);
        }
    };

    auto loadb = [&](int w) {
#pragma unroll
        for (int fj = 0; fj < 4; fj++) {
            size_t wo = (size_t)(n0 + n_off + fj * 16 + l15) * D
                      + w * 32 + quad * 8;
            bh[fj] = *(const half8*)(Wh + wo);
            bl[fj] = *(const half8*)(Wl + wo);
        }
    };

    // Read A fragment from LDS (swizzled), split to hi/lo, 3 MFMAs per acc.
    auto compute = [&](int w) {
#pragma unroll
        for (int fi = 0; fi < 4; fi++) {
            int r = m_off + fi * 16 + l15;
            const float4* Ar = (const float4*)&As[w & 1][r * 32];
            int u0 = (quad * 2) ^ (r & 7);
            float4 v0 = Ar[u0];
            float4 v1 = Ar[u0 ^ 1];
            float f[8] = {v0.x, v0.y, v0.z, v0.w, v1.x, v1.y, v1.z, v1.w};
            half8 ah, al;
#pragma unroll
            for (int j = 0; j < 8; j++) {
                _Float16 h = (_Float16)f[j];
                ah[j] = h;
                al[j] = (_Float16)(f[j] - (float)h);
            }
#pragma unroll
            for (int fj = 0; fj < 4; fj++) {
                acc[fi][fj] = __builtin_amdgcn_mfma_f32_16x16x32_f16(
                    ah, bh[fj], acc[fi][fj], 0, 0, 0);
                acc[fi][fj] = __builtin_amdgcn_mfma_f32_16x16x32_f16(
                    ah, bl[fj], acc[fi][fj], 0, 0, 0);
                acc[fi][fj] = __builtin_amdgcn_mfma_f32_16x16x32_f16(
                    al, bh[fj], acc[fi][fj], 0, 0, 0);
            }
        }
    };

    // prologue
    stage(0);
    loadb(0);
    stage(1);
    asm volatile("s_waitcnt vmcnt(4)" ::: "memory");   // drain S0+B0, keep S1
    __builtin_amdgcn_s_barrier();
    __builtin_amdgcn_sched_barrier(0);
    compute(0);
    __builtin_amdgcn_s_barrier();

    // steady state: ledger entering iter w: 4 outstanding (S(w)).
    // +8 loadb(w) +4 stage(w+1) = 16; vmcnt(4) leaves the 4 newest (S(w+1));
    // S(w) is older than all 12 new ops -> always drained.
#pragma unroll
    for (int w = 1; w < 7; w++) {
        loadb(w);
        stage(w + 1);
        asm volatile("s_waitcnt vmcnt(4)" ::: "memory");
        __builtin_amdgcn_s_barrier();
        __builtin_amdgcn_sched_barrier(0);
        compute(w);
        __builtin_amdgcn_s_barrier();
    }

    // last window: nothing left to stage
    loadb(7);
    asm volatile("s_waitcnt vmcnt(0)" ::: "memory");
    __builtin_amdgcn_s_barrier();
    __builtin_amdgcn_sched_barrier(0);
    compute(7);

    // ---- epilogue: direct fp32 stores (C layout: row=quad*4+q, col=l15) ----
#pragma unroll
    for (int fi = 0; fi < 4; fi++)
#pragma unroll
        for (int fj = 0; fj < 4; fj++)
#pragma unroll
            for (int q = 0; q < 4; q++) {
                int row = m0 + m_off + fi * 16 + quad * 4 + q;
                int col = n0 + n_off + fj * 16 + l15;
                G[(size_t)row * D + col] = acc[fi][fj][q];
            }
}

// ---------------------------------------------------------------------------
// K4: recurrence. One wave per doc; lane l owns dims 4l..4l+3 of s.
//     Depth-4 prefetch; fast tanh/sigmoid via v_exp + v_rcp (err ~1e-6).
// ---------------------------------------------------------------------------
__device__ __forceinline__ float ftanh(float x)
{
    float e = __expf(2.0f * x);
    return 1.0f - 2.0f * __builtin_amdgcn_rcpf(e + 1.0f);
}

__global__ __launch_bounds__(256) void k4_recur(
    const float* __restrict__ sent, const float* __restrict__ G,
    const float* __restrict__ uw, const float* __restrict__ abs_w,
    const float* __restrict__ relw, const float* __restrict__ bias,
    const int* __restrict__ dls, const int* __restrict__ offs,
    float* __restrict__ out)
{
    int wave = threadIdx.x >> 6;
    int lane = threadIdx.x & 63;
    int b = blockIdx.x * 4 + wave;

    int dl = dls[b];
    float dlf = (float)dl;
    int base = offs[b];
    float bs = bias[0];

    const float4* h_ptr = (const float4*)(sent + (size_t)b * L * D) + lane;
    const float4* g_ptr = (const float4*)(G + (size_t)b * L * D) + lane;
    float4 uwv = ((const float4*)(uw + (size_t)b * D))[lane];

    float4 s = make_float4(0.f, 0.f, 0.f, 0.f);

    float4 h0 = h_ptr[0 * (D / 4)], g0 = g_ptr[0 * (D / 4)];
    float4 h1 = h_ptr[1 * (D / 4)], g1 = g_ptr[1 * (D / 4)];
    float4 h2 = h_ptr[2 * (D / 4)], g2 = g_ptr[2 * (D / 4)];
    float4 h3 = h_ptr[3 * (D / 4)], g3 = g_ptr[3 * (D / 4)];

    auto step = [&](float4& HH, float4& GG, int tt) {
        int tp = tt + 4; if (tp >= L) tp = 0;
        float4 hn = h_ptr[(size_t)tp * (D / 4)];
        float4 gn = g_ptr[(size_t)tp * (D / 4)];
        float4 ts;
        ts.x = ftanh(s.x); ts.y = ftanh(s.y);
        ts.z = ftanh(s.z); ts.w = ftanh(s.w);
        float r = HH.x * uwv.x + HH.y * uwv.y + HH.z * uwv.z + HH.w * uwv.w
                - (GG.x * ts.x + GG.y * ts.y + GG.z * ts.z + GG.w * ts.w);
        r += __shfl_xor(r, 32, 64);
        r += __shfl_xor(r, 16, 64);
        r += __shfl_xor(r, 8, 64);
        r += __shfl_xor(r, 4, 64);
        r += __shfl_xor(r, 2, 64);
        r += __shfl_xor(r, 1, 64);
        bool valid = tt < dl;
        int ta = valid ? tt : 0;
        int idx = (int)rintf((float)(tt + 1) * 9.0f / dlf);
        if (idx > 24) idx = 24;
        float pre = r + abs_w[ta] + relw[idx] + bs;
        float p = __builtin_amdgcn_rcpf(1.0f + __expf(-pre));
        float pm = valid ? p : 0.0f;
        s.x += pm * HH.x; s.y += pm * HH.y;
        s.z += pm * HH.z; s.w += pm * HH.w;
        if (valid && lane == 0) out[base + tt] = p;
        HH = hn; GG = gn;
    };

    int nsteps = (dl + 3) & ~3;
    for (int t = 0; t < nsteps; t += 4) {
        step(h0, g0, t);
        step(h1, g1, t + 1);
        step(h2, g2, t + 2);
        step(h3, g3, t + 3);
    }
}

// ---------------------------------------------------------------------------
extern "C" void kernel_launch(void* const* d_in, const int* in_sizes, int n_in,
                              void* d_out, int out_size, void* d_ws, size_t ws_size,
                              hipStream_t stream)
{
    const float* sent      = (const float*)d_in[0];
    const float* fc_w      = (const float*)d_in[1];
    const float* fc_b      = (const float*)d_in[2];
    const float* w_content = (const float*)d_in[3];
    const float* W_sal     = (const float*)d_in[4];
    const float* W_nov     = (const float*)d_in[5];
    const float* abs_embed = (const float*)d_in[6];
    const float* rel_embed = (const float*)d_in[7];
    const float* w_abs     = (const float*)d_in[8];
    const float* w_rel     = (const float*)d_in[9];
    const float* bias      = (const float*)d_in[10];
    const int*   dls       = (const int*)d_in[11];
    float* out = (float*)d_out;

    // workspace layout (bytes)
    char* ws = (char*)d_ws;
    int*      offs  = (int*)ws;                                   // 8 KiB
    float*    abs_w = (float*)(ws + 8192);                        // 512 B
    float*    relw  = (float*)(ws + 8704);                        // 512 B
    float*    docs  = (float*)(ws + 9216);                        // 2 MiB
    float*    uw    = (float*)(ws + 9216 + (size_t)B * D * 4);    // 2 MiB
    _Float16* Wh    = (_Float16*)(ws + 9216 + 2 * (size_t)B * D * 4);          // 128 KiB
    _Float16* Wl    = (_Float16*)(ws + 9216 + 2 * (size_t)B * D * 4 + 131072); // 128 KiB
    float*    G     = (float*)(ws + 9216 + 2 * (size_t)B * D * 4 + 262144);    // 200 MiB

    hipLaunchKernelGGL(k0_precompute, dim3(1), dim3(256), 0, stream,
                       abs_embed, w_abs, rel_embed, w_rel, dls, abs_w, relw, offs);
    hipLaunchKernelGGL(k0b_wt, dim3(D), dim3(D), 0, stream, W_nov, Wh, Wl);
    hipLaunchKernelGGL(k1_docavg, dim3(B / 4), dim3(256), 0, stream, sent, dls, docs);
    hipLaunchKernelGGL(k2_docrep, dim3(B / 8), dim3(256), 0, stream,
                       docs, fc_w, fc_b, W_sal, w_content, uw);
    hipLaunchKernelGGL(k3_mfma, dim3(2, 800), dim3(256), 0, stream,
                       sent, Wh, Wl, G, 0);
    hipLaunchKernelGGL(k3_mfma, dim3(2, 800), dim3(256), 0, stream,
                       sent, Wh, Wl, G, 800);
    hipLaunchKernelGGL(k4_recur, dim3(B / 4), dim3(256), 0, stream,
                       sent, G, uw, abs_w, relw, bias, dls, offs, out);
}

// Round 7
// 569.673 us; speedup vs baseline: 1.0188x; 1.0188x over previous
//
#include <hip/hip_runtime.h>
#include <hip/hip_bf16.h>
#include <math.h>

#define B 2048
#define L 100
#define D 256

typedef _Float16 half8 __attribute__((ext_vector_type(8)));
typedef __attribute__((ext_vector_type(4))) float f32x4;

// ---------------------------------------------------------------------------
// K0: abs_w[t] = abs_embed[t]·w_abs, relw[i] = rel_embed[i]·w_rel,
//     exclusive scan of doc_lens.
// ---------------------------------------------------------------------------
__global__ __launch_bounds__(256) void k0_precompute(
    const float* __restrict__ abs_embed, const float* __restrict__ w_abs,
    const float* __restrict__ rel_embed, const float* __restrict__ w_rel,
    const int* __restrict__ dls,
    float* __restrict__ abs_w, float* __restrict__ relw, int* __restrict__ offs)
{
    int t = threadIdx.x;
    if (t < 100) {
        float s = 0.f;
        for (int j = 0; j < 50; j++) s += abs_embed[t * 50 + j] * w_abs[j];
        abs_w[t] = s;
    }
    if (t < 25) {
        float s = 0.f;
        for (int j = 0; j < 50; j++) s += rel_embed[t * 50 + j] * w_rel[j];
        relw[t] = s;
    }
    __shared__ int lds[256];
    int loc[8];
    int sum = 0;
    for (int k = 0; k < 8; k++) { loc[k] = sum; sum += dls[t * 8 + k]; }
    lds[t] = sum;
    __syncthreads();
    for (int off = 1; off < 256; off <<= 1) {
        int v = (t >= off) ? lds[t - off] : 0;
        __syncthreads();
        lds[t] += v;
        __syncthreads();
    }
    int base = (t > 0) ? lds[t - 1] : 0;
    for (int k = 0; k < 8; k++) offs[t * 8 + k] = base + loc[k];
}

// ---------------------------------------------------------------------------
// K0b: split-fp16 transpose of W_nov: Wh/Wl are [N][K] fp16,
//      W = Wh + Wl with |err| <= 2^-22 rel.  (2 x 128 KB, L2-resident)
// ---------------------------------------------------------------------------
__global__ __launch_bounds__(256) void k0b_wt(
    const float* __restrict__ W, _Float16* __restrict__ Wh, _Float16* __restrict__ Wl)
{
    int n = blockIdx.x, k = threadIdx.x;
    float w = W[k * D + n];
    _Float16 hi = (_Float16)w;
    _Float16 lo = (_Float16)(w - (float)hi);
    Wh[n * D + k] = hi;
    Wl[n * D + k] = lo;
}

// ---------------------------------------------------------------------------
// K1: docs[b,d] = sum_{t<dl} sent[b,t,d] / dl
//     One WAVE per doc; 4-row unrolled so 4 independent 1 KB loads are in
//     flight per latency exposure.
// ---------------------------------------------------------------------------
__global__ __launch_bounds__(256) void k1_docavg(
    const float* __restrict__ sent, const int* __restrict__ dls,
    float* __restrict__ docs)
{
    int wave = threadIdx.x >> 6;
    int lane = threadIdx.x & 63;
    int b = blockIdx.x * 4 + wave;
    int dl = dls[b];
    const float4* p = (const float4*)(sent + (size_t)b * L * D) + lane;
    float4 s = make_float4(0.f, 0.f, 0.f, 0.f);
    int t = 0;
    for (; t + 4 <= dl; t += 4) {
        float4 a = p[(size_t)t * (D / 4)];
        float4 c = p[(size_t)(t + 1) * (D / 4)];
        float4 e = p[(size_t)(t + 2) * (D / 4)];
        float4 f = p[(size_t)(t + 3) * (D / 4)];
        s.x += (a.x + c.x) + (e.x + f.x);
        s.y += (a.y + c.y) + (e.y + f.y);
        s.z += (a.z + c.z) + (e.z + f.z);
        s.w += (a.w + c.w) + (e.w + f.w);
    }
    for (; t < dl; t++) {
        float4 a = p[(size_t)t * (D / 4)];
        s.x += a.x; s.y += a.y; s.z += a.z; s.w += a.w;
    }
    float inv = 1.0f / (float)dl;
    float4 r = make_float4(s.x * inv, s.y * inv, s.z * inv, s.w * inv);
    ((float4*)(docs + (size_t)b * D))[lane] = r;
}

// ---------------------------------------------------------------------------
// K2: doc = tanh(docs @ fc_w.T + fc_b); uw = W_sal @ doc + w_content
// ---------------------------------------------------------------------------
__global__ __launch_bounds__(256) void k2_docrep(
    const float* __restrict__ docs, const float* __restrict__ fc_w,
    const float* __restrict__ fc_b, const float* __restrict__ W_sal,
    const float* __restrict__ w_content, float* __restrict__ uw)
{
    __shared__ float sd[8][D];
    __shared__ float sdoc[8][D];
    int g = blockIdx.x;
    int i = threadIdx.x;

    for (int dd = 0; dd < 8; dd++) sd[dd][i] = docs[(size_t)(g * 8 + dd) * D + i];
    __syncthreads();

    float acc[8];
    float fb = fc_b[i];
#pragma unroll
    for (int dd = 0; dd < 8; dd++) acc[dd] = fb;
    const float4* wr = (const float4*)(fc_w + (size_t)i * D);
    for (int j = 0; j < D / 4; j++) {
        float4 w = wr[j];
#pragma unroll
        for (int dd = 0; dd < 8; dd++) {
            float4 v = ((const float4*)sd[dd])[j];
            acc[dd] += w.x * v.x + w.y * v.y + w.z * v.z + w.w * v.w;
        }
    }
#pragma unroll
    for (int dd = 0; dd < 8; dd++) sdoc[dd][i] = tanhf(acc[dd]);
    __syncthreads();

    float acc2[8];
#pragma unroll
    for (int dd = 0; dd < 8; dd++) acc2[dd] = 0.f;
    const float4* wsr = (const float4*)(W_sal + (size_t)i * D);
    for (int j = 0; j < D / 4; j++) {
        float4 w = wsr[j];
#pragma unroll
        for (int dd = 0; dd < 8; dd++) {
            float4 v = ((const float4*)sdoc[dd])[j];
            acc2[dd] += w.x * v.x + w.y * v.y + w.z * v.z + w.w * v.w;
        }
    }
    float wc = w_content[i];
#pragma unroll
    for (int dd = 0; dd < 8; dd++)
        uw[(size_t)(g * 8 + dd) * D + i] = acc2[dd] + wc;
}

// ---------------------------------------------------------------------------
// K3: G(fp32) = sent @ W_nov via split-fp16 MFMA (hi*hi + hi*lo + lo*hi).
//     Depth-2 async pipeline:
//       - A-tile: BK=32, TRIPLE-buffered 3x16 KB LDS (48 KB -> 3 blocks/CU),
//         staged via global_load_lds w16, XOR-swizzled 16B granules
//         (slot u holds global chunk u^(r&7); linear dest + pre-swizzled
//         source + swizzled read).
//       - B fragments: double-buffered in REGISTERS, prefetched one window
//         ahead (bhA/blA vs bhB/blB by window parity).
//     Issue order: S0 B0 S1 B1 S2, then per window: wait/compute(w),
//     loadb(w+2), stage(w+3).  Steady-state outstanding entering window w:
//     S(w) B(w) S(w+1) B(w+1) S(w+2) = 28 ops; vmcnt(16) drains exactly
//     the 12 oldest = S(w)+B(w).  Tail: vmcnt(12) at w=6, vmcnt(0) at w=7.
//     k-granule accumulation order identical to prior rounds -> bit-identical G.
// ---------------------------------------------------------------------------
__global__ __launch_bounds__(256, 3) void k3_mfma(
    const float* __restrict__ A, const _Float16* __restrict__ Wh,
    const _Float16* __restrict__ Wl, float* __restrict__ G)
{
    __shared__ __align__(16) float As[3][128 * 32];   // 3 x 16 KB

    int tid = threadIdx.x;
    int lane = tid & 63;
    int wv = tid >> 6;
    int n0 = blockIdx.x * 128;           // gridDim.x = 2
    int m0 = blockIdx.y * 128;
    int m_off = (wv & 1) * 64;
    int n_off = (wv >> 1) * 64;
    int quad = lane >> 4;
    int l15 = lane & 15;

    f32x4 acc[4][4];
#pragma unroll
    for (int fi = 0; fi < 4; fi++)
#pragma unroll
        for (int fj = 0; fj < 4; fj++) acc[fi][fj] = (f32x4){0.f, 0.f, 0.f, 0.f};

    half8 bhA[4], blA[4], bhB[4], blB[4];

    // Stage K-window w (floats w*32..w*32+31) into LDS buffer w%3.
    // Granule g = i*256 + wv*64 + lane: row r = g>>3, slot u = g&7 holds
    // global chunk u^(r&7).  Dest wave-uniform base (+lane*16 implicit).
    auto stage = [&](int w) {
#pragma unroll
        for (int i = 0; i < 4; i++) {
            int flat = i * 256 + tid;
            int r = flat >> 3, u = flat & 7;
            int us = u ^ (r & 7);
            const float* src = A + (size_t)(m0 + r) * D + w * 32 + us * 4;
            float* dst = &As[w % 3][(i * 256 + wv * 64) * 4];
            __builtin_amdgcn_global_load_lds(
                (const __attribute__((address_space(1))) void*)src,
                (__attribute__((address_space(3))) void*)dst, 16, 0, 0);
        }
    };

    auto loadb = [&](int w, half8* BH, half8* BL) {
#pragma unroll
        for (int fj = 0; fj < 4; fj++) {
            size_t wo = (size_t)(n0 + n_off + fj * 16 + l15) * D
                      + w * 32 + quad * 8;
            BH[fj] = *(const half8*)(Wh + wo);
            BL[fj] = *(const half8*)(Wl + wo);
        }
    };

    // Read A fragment from LDS (swizzled), split to hi/lo, 3 MFMAs per acc.
    auto compute = [&](int w, const half8* BH, const half8* BL) {
#pragma unroll
        for (int fi = 0; fi < 4; fi++) {
            int r = m_off + fi * 16 + l15;
            const float4* Ar = (const float4*)&As[w % 3][r * 32];
            int u0 = (quad * 2) ^ (r & 7);
            float4 v0 = Ar[u0];
            float4 v1 = Ar[u0 ^ 1];
            float f[8] = {v0.x, v0.y, v0.z, v0.w, v1.x, v1.y, v1.z, v1.w};
            half8 ah, al;
#pragma unroll
            for (int j = 0; j < 8; j++) {
                _Float16 h = (_Float16)f[j];
                ah[j] = h;
                al[j] = (_Float16)(f[j] - (float)h);
            }
#pragma unroll
            for (int fj = 0; fj < 4; fj++) {
                acc[fi][fj] = __builtin_amdgcn_mfma_f32_16x16x32_f16(
                    ah, BH[fj], acc[fi][fj], 0, 0, 0);
                acc[fi][fj] = __builtin_amdgcn_mfma_f32_16x16x32_f16(
                    ah, BL[fj], acc[fi][fj], 0, 0, 0);
                acc[fi][fj] = __builtin_amdgcn_mfma_f32_16x16x32_f16(
                    al, BH[fj], acc[fi][fj], 0, 0, 0);
            }
        }
    };

    // prologue: S0 B0 S1 B1 S2 (28 ops outstanding), sched_barrier pins order
    stage(0);               __builtin_amdgcn_sched_barrier(0);
    loadb(0, bhA, blA);     __builtin_amdgcn_sched_barrier(0);
    stage(1);               __builtin_amdgcn_sched_barrier(0);
    loadb(1, bhB, blB);     __builtin_amdgcn_sched_barrier(0);
    stage(2);               __builtin_amdgcn_sched_barrier(0);

#pragma unroll
    for (int w = 0; w < 8; w++) {
        if (w <= 5)      asm volatile("s_waitcnt vmcnt(16)" ::: "memory");
        else if (w == 6) asm volatile("s_waitcnt vmcnt(12)" ::: "memory");
        else             asm volatile("s_waitcnt vmcnt(0)"  ::: "memory");
        __builtin_amdgcn_s_barrier();
        __builtin_amdgcn_sched_barrier(0);
        if (w & 1) compute(w, bhB, blB);
        else       compute(w, bhA, blA);
        __builtin_amdgcn_s_barrier();       // readers done before re-stage
        __builtin_amdgcn_sched_barrier(0);
        if (w + 2 <= 7) {
            if (w & 1) loadb(w + 2, bhB, blB);   // set free after compute(w)
            else       loadb(w + 2, bhA, blA);
            __builtin_amdgcn_sched_barrier(0);
        }
        if (w + 3 <= 7) {
            stage(w + 3);                        // writes buffer (w)%3
            __builtin_amdgcn_sched_barrier(0);
        }
    }

    // ---- epilogue: direct fp32 stores (C layout: row=quad*4+q, col=l15) ----
#pragma unroll
    for (int fi = 0; fi < 4; fi++)
#pragma unroll
        for (int fj = 0; fj < 4; fj++)
#pragma unroll
            for (int q = 0; q < 4; q++) {
                int row = m0 + m_off + fi * 16 + quad * 4 + q;
                int col = n0 + n_off + fj * 16 + l15;
                G[(size_t)row * D + col] = acc[fi][fj][q];
            }
}

// ---------------------------------------------------------------------------
// K4: recurrence. One wave per doc; lane l owns dims 4l..4l+3 of s.
//     Depth-4 prefetch; fast tanh/sigmoid via v_exp + v_rcp (err ~1e-6).
// ---------------------------------------------------------------------------
__device__ __forceinline__ float ftanh(float x)
{
    float e = __expf(2.0f * x);
    return 1.0f - 2.0f * __builtin_amdgcn_rcpf(e + 1.0f);
}

__global__ __launch_bounds__(256) void k4_recur(
    const float* __restrict__ sent, const float* __restrict__ G,
    const float* __restrict__ uw, const float* __restrict__ abs_w,
    const float* __restrict__ relw, const float* __restrict__ bias,
    const int* __restrict__ dls, const int* __restrict__ offs,
    float* __restrict__ out)
{
    int wave = threadIdx.x >> 6;
    int lane = threadIdx.x & 63;
    int b = blockIdx.x * 4 + wave;

    int dl = dls[b];
    float dlf = (float)dl;
    int base = offs[b];
    float bs = bias[0];

    const float4* h_ptr = (const float4*)(sent + (size_t)b * L * D) + lane;
    const float4* g_ptr = (const float4*)(G + (size_t)b * L * D) + lane;
    float4 uwv = ((const float4*)(uw + (size_t)b * D))[lane];

    float4 s = make_float4(0.f, 0.f, 0.f, 0.f);

    float4 h0 = h_ptr[0 * (D / 4)], g0 = g_ptr[0 * (D / 4)];
    float4 h1 = h_ptr[1 * (D / 4)], g1 = g_ptr[1 * (D / 4)];
    float4 h2 = h_ptr[2 * (D / 4)], g2 = g_ptr[2 * (D / 4)];
    float4 h3 = h_ptr[3 * (D / 4)], g3 = g_ptr[3 * (D / 4)];

    auto step = [&](float4& HH, float4& GG, int tt) {
        int tp = tt + 4; if (tp >= L) tp = 0;
        float4 hn = h_ptr[(size_t)tp * (D / 4)];
        float4 gn = g_ptr[(size_t)tp * (D / 4)];
        float4 ts;
        ts.x = ftanh(s.x); ts.y = ftanh(s.y);
        ts.z = ftanh(s.z); ts.w = ftanh(s.w);
        float r = HH.x * uwv.x + HH.y * uwv.y + HH.z * uwv.z + HH.w * uwv.w
                - (GG.x * ts.x + GG.y * ts.y + GG.z * ts.z + GG.w * ts.w);
        r += __shfl_xor(r, 32, 64);
        r += __shfl_xor(r, 16, 64);
        r += __shfl_xor(r, 8, 64);
        r += __shfl_xor(r, 4, 64);
        r += __shfl_xor(r, 2, 64);
        r += __shfl_xor(r, 1, 64);
        bool valid = tt < dl;
        int ta = valid ? tt : 0;
        int idx = (int)rintf((float)(tt + 1) * 9.0f / dlf);
        if (idx > 24) idx = 24;
        float pre = r + abs_w[ta] + relw[idx] + bs;
        float p = __builtin_amdgcn_rcpf(1.0f + __expf(-pre));
        float pm = valid ? p : 0.0f;
        s.x += pm * HH.x; s.y += pm * HH.y;
        s.z += pm * HH.z; s.w += pm * HH.w;
        if (valid && lane == 0) out[base + tt] = p;
        HH = hn; GG = gn;
    };

    int nsteps = (dl + 3) & ~3;
    for (int t = 0; t < nsteps; t += 4) {
        step(h0, g0, t);
        step(h1, g1, t + 1);
        step(h2, g2, t + 2);
        step(h3, g3, t + 3);
    }
}

// ---------------------------------------------------------------------------
extern "C" void kernel_launch(void* const* d_in, const int* in_sizes, int n_in,
                              void* d_out, int out_size, void* d_ws, size_t ws_size,
                              hipStream_t stream)
{
    const float* sent      = (const float*)d_in[0];
    const float* fc_w      = (const float*)d_in[1];
    const float* fc_b      = (const float*)d_in[2];
    const float* w_content = (const float*)d_in[3];
    const float* W_sal     = (const float*)d_in[4];
    const float* W_nov     = (const float*)d_in[5];
    const float* abs_embed = (const float*)d_in[6];
    const float* rel_embed = (const float*)d_in[7];
    const float* w_abs     = (const float*)d_in[8];
    const float* w_rel     = (const float*)d_in[9];
    const float* bias      = (const float*)d_in[10];
    const int*   dls       = (const int*)d_in[11];
    float* out = (float*)d_out;

    // workspace layout (bytes)
    char* ws = (char*)d_ws;
    int*      offs  = (int*)ws;                                   // 8 KiB
    float*    abs_w = (float*)(ws + 8192);                        // 512 B
    float*    relw  = (float*)(ws + 8704);                        // 512 B
    float*    docs  = (float*)(ws + 9216);                        // 2 MiB
    float*    uw    = (float*)(ws + 9216 + (size_t)B * D * 4);    // 2 MiB
    _Float16* Wh    = (_Float16*)(ws + 9216 + 2 * (size_t)B * D * 4);          // 128 KiB
    _Float16* Wl    = (_Float16*)(ws + 9216 + 2 * (size_t)B * D * 4 + 131072); // 128 KiB
    float*    G     = (float*)(ws + 9216 + 2 * (size_t)B * D * 4 + 262144);    // 200 MiB

    hipLaunchKernelGGL(k0_precompute, dim3(1), dim3(256), 0, stream,
                       abs_embed, w_abs, rel_embed, w_rel, dls, abs_w, relw, offs);
    hipLaunchKernelGGL(k0b_wt, dim3(D), dim3(D), 0, stream, W_nov, Wh, Wl);
    hipLaunchKernelGGL(k1_docavg, dim3(B / 4), dim3(256), 0, stream, sent, dls, docs);
    hipLaunchKernelGGL(k2_docrep, dim3(B / 8), dim3(256), 0, stream,
                       docs, fc_w, fc_b, W_sal, w_content, uw);
    hipLaunchKernelGGL(k3_mfma, dim3(2, (B * L) / 128), dim3(256), 0, stream,
                       sent, Wh, Wl, G);
    hipLaunchKernelGGL(k4_recur, dim3(B / 4), dim3(256), 0, stream,
                       sent, G, uw, abs_w, relw, bias, dls, offs, out);
}

// Round 9
// 473.380 us; speedup vs baseline: 1.2261x; 1.2034x over previous
//
#include <hip/hip_runtime.h>
#include <hip/hip_bf16.h>
#include <math.h>

#define B 2048
#define L 100
#define D 256
#define NROWS (B * L)

typedef _Float16 half8 __attribute__((ext_vector_type(8)));
typedef __attribute__((ext_vector_type(4))) float f32x4;

// ---------------------------------------------------------------------------
// K0: abs_w[t] = abs_embed[t]·w_abs, relw[i] = rel_embed[i]·w_rel,
//     exclusive scan of doc_lens; offs[2048] = total valid rows.
// ---------------------------------------------------------------------------
__global__ __launch_bounds__(256) void k0_precompute(
    const float* __restrict__ abs_embed, const float* __restrict__ w_abs,
    const float* __restrict__ rel_embed, const float* __restrict__ w_rel,
    const int* __restrict__ dls,
    float* __restrict__ abs_w, float* __restrict__ relw, int* __restrict__ offs)
{
    int t = threadIdx.x;
    if (t < 100) {
        float s = 0.f;
        for (int j = 0; j < 50; j++) s += abs_embed[t * 50 + j] * w_abs[j];
        abs_w[t] = s;
    }
    if (t < 25) {
        float s = 0.f;
        for (int j = 0; j < 50; j++) s += rel_embed[t * 50 + j] * w_rel[j];
        relw[t] = s;
    }
    __shared__ int lds[256];
    int loc[8];
    int sum = 0;
    for (int k = 0; k < 8; k++) { loc[k] = sum; sum += dls[t * 8 + k]; }
    lds[t] = sum;
    __syncthreads();
    for (int off = 1; off < 256; off <<= 1) {
        int v = (t >= off) ? lds[t - off] : 0;
        __syncthreads();
        lds[t] += v;
        __syncthreads();
    }
    int base = (t > 0) ? lds[t - 1] : 0;
    for (int k = 0; k < 8; k++) offs[t * 8 + k] = base + loc[k];
    if (t == 255) offs[2048] = lds[255];          // vtotal
}

// ---------------------------------------------------------------------------
// K0c: row_map[offs[b]+t] = b*L+t for t < dl[b]  (compact valid-row index)
// ---------------------------------------------------------------------------
__global__ __launch_bounds__(128) void k0c_rowmap(
    const int* __restrict__ dls, const int* __restrict__ offs,
    int* __restrict__ row_map)
{
    int b = blockIdx.x, t = threadIdx.x;
    if (t < dls[b]) row_map[offs[b] + t] = b * L + t;
}

// ---------------------------------------------------------------------------
// K0b: split-fp16 transpose of W_nov: Wh/Wl are [N][K] fp16,
//      W = Wh + Wl with |err| <= 2^-22 rel.  (2 x 128 KB, L2-resident)
// ---------------------------------------------------------------------------
__global__ __launch_bounds__(256) void k0b_wt(
    const float* __restrict__ W, _Float16* __restrict__ Wh, _Float16* __restrict__ Wl)
{
    int n = blockIdx.x, k = threadIdx.x;
    float w = W[k * D + n];
    _Float16 hi = (_Float16)w;
    _Float16 lo = (_Float16)(w - (float)hi);
    Wh[n * D + k] = hi;
    Wl[n * D + k] = lo;
}

// ---------------------------------------------------------------------------
// K1: docs[b,d] = sum_{t<dl} sent[b,t,d] / dl
// ---------------------------------------------------------------------------
__global__ __launch_bounds__(256) void k1_docavg(
    const float* __restrict__ sent, const int* __restrict__ dls,
    float* __restrict__ docs)
{
    int wave = threadIdx.x >> 6;
    int lane = threadIdx.x & 63;
    int b = blockIdx.x * 4 + wave;
    int dl = dls[b];
    const float4* p = (const float4*)(sent + (size_t)b * L * D) + lane;
    float4 s = make_float4(0.f, 0.f, 0.f, 0.f);
    int t = 0;
    for (; t + 4 <= dl; t += 4) {
        float4 a = p[(size_t)t * (D / 4)];
        float4 c = p[(size_t)(t + 1) * (D / 4)];
        float4 e = p[(size_t)(t + 2) * (D / 4)];
        float4 f = p[(size_t)(t + 3) * (D / 4)];
        s.x += (a.x + c.x) + (e.x + f.x);
        s.y += (a.y + c.y) + (e.y + f.y);
        s.z += (a.z + c.z) + (e.z + f.z);
        s.w += (a.w + c.w) + (e.w + f.w);
    }
    for (; t < dl; t++) {
        float4 a = p[(size_t)t * (D / 4)];
        s.x += a.x; s.y += a.y; s.z += a.z; s.w += a.w;
    }
    float inv = 1.0f / (float)dl;
    float4 r = make_float4(s.x * inv, s.y * inv, s.z * inv, s.w * inv);
    ((float4*)(docs + (size_t)b * D))[lane] = r;
}

// ---------------------------------------------------------------------------
// K2: doc = tanh(docs @ fc_w.T + fc_b); uw = W_sal @ doc + w_content
// ---------------------------------------------------------------------------
__global__ __launch_bounds__(256) void k2_docrep(
    const float* __restrict__ docs, const float* __restrict__ fc_w,
    const float* __restrict__ fc_b, const float* __restrict__ W_sal,
    const float* __restrict__ w_content, float* __restrict__ uw)
{
    __shared__ float sd[8][D];
    __shared__ float sdoc[8][D];
    int g = blockIdx.x;
    int i = threadIdx.x;

    for (int dd = 0; dd < 8; dd++) sd[dd][i] = docs[(size_t)(g * 8 + dd) * D + i];
    __syncthreads();

    float acc[8];
    float fb = fc_b[i];
#pragma unroll
    for (int dd = 0; dd < 8; dd++) acc[dd] = fb;
    const float4* wr = (const float4*)(fc_w + (size_t)i * D);
    for (int j = 0; j < D / 4; j++) {
        float4 w = wr[j];
#pragma unroll
        for (int dd = 0; dd < 8; dd++) {
            float4 v = ((const float4*)sd[dd])[j];
            acc[dd] += w.x * v.x + w.y * v.y + w.z * v.z + w.w * v.w;
        }
    }
#pragma unroll
    for (int dd = 0; dd < 8; dd++) sdoc[dd][i] = tanhf(acc[dd]);
    __syncthreads();

    float acc2[8];
#pragma unroll
    for (int dd = 0; dd < 8; dd++) acc2[dd] = 0.f;
    const float4* wsr = (const float4*)(W_sal + (size_t)i * D);
    for (int j = 0; j < D / 4; j++) {
        float4 w = wsr[j];
#pragma unroll
        for (int dd = 0; dd < 8; dd++) {
            float4 v = ((const float4*)sdoc[dd])[j];
            acc2[dd] += w.x * v.x + w.y * v.y + w.z * v.z + w.w * v.w;
        }
    }
    float wc = w_content[i];
#pragma unroll
    for (int dd = 0; dd < 8; dd++)
        uw[(size_t)(g * 8 + dd) * D + i] = acc2[dd] + wc;
}

// ---------------------------------------------------------------------------
// K3: compact-row G = sent[valid rows] @ W_nov, split-fp16 MFMA.
//     Only vtotal (= sum dl, ~103K of 204K) rows are computed; A rows are
//     gathered through row_map (per-thread row bases in registers), G is
//     written COMPACTED (row offs[b]+t).  Pipeline = round-7 structure:
//     BK=32, triple-buffered 3x16 KB LDS, B regs double-buffered one window
//     ahead, counted vmcnt(16); XOR-swizzled 16B granules.
//     Per-valid-row arithmetic identical -> bit-identical G rows.
// ---------------------------------------------------------------------------
__global__ __launch_bounds__(256, 3) void k3_mfma(
    const float* __restrict__ A, const _Float16* __restrict__ Wh,
    const _Float16* __restrict__ Wl, const int* __restrict__ row_map,
    const int* __restrict__ offs, float* __restrict__ G)
{
    __shared__ __align__(16) float As[3][128 * 32];   // 3 x 16 KB

    int vtotal = offs[2048];
    int m0 = blockIdx.y * 128;
    if (m0 >= vtotal) return;                 // uniform early-exit (tail tiles)

    int tid = threadIdx.x;
    int lane = tid & 63;
    int wv = tid >> 6;
    int n0 = blockIdx.x * 128;                // gridDim.x = 2
    int m_off = (wv & 1) * 64;
    int n_off = (wv >> 1) * 64;
    int quad = lane >> 4;
    int l15 = lane & 15;

    // per-thread A gather bases: granule g = i*256+tid -> row r = g>>3
    const float* srcb[4];
#pragma unroll
    for (int i = 0; i < 4; i++) {
        int flat = i * 256 + tid;
        int r = flat >> 3, u = flat & 7;
        int us = u ^ (r & 7);
        unsigned rb = (unsigned)row_map[m0 + r];
        if (rb > (unsigned)(NROWS - 1)) rb = 0;       // clamp poison in tail
        srcb[i] = A + (size_t)rb * D + us * 4;
    }

    f32x4 acc[4][4];
#pragma unroll
    for (int fi = 0; fi < 4; fi++)
#pragma unroll
        for (int fj = 0; fj < 4; fj++) acc[fi][fj] = (f32x4){0.f, 0.f, 0.f, 0.f};

    half8 bhA[4], blA[4], bhB[4], blB[4];

    auto stage = [&](int w) {
#pragma unroll
        for (int i = 0; i < 4; i++) {
            const float* src = srcb[i] + w * 32;
            float* dst = &As[w % 3][(i * 256 + wv * 64) * 4];
            __builtin_amdgcn_global_load_lds(
                (const __attribute__((address_space(1))) void*)src,
                (__attribute__((address_space(3))) void*)dst, 16, 0, 0);
        }
    };

    auto loadb = [&](int w, half8* BH, half8* BL) {
#pragma unroll
        for (int fj = 0; fj < 4; fj++) {
            size_t wo = (size_t)(n0 + n_off + fj * 16 + l15) * D
                      + w * 32 + quad * 8;
            BH[fj] = *(const half8*)(Wh + wo);
            BL[fj] = *(const half8*)(Wl + wo);
        }
    };

    auto compute = [&](int w, const half8* BH, const half8* BL) {
#pragma unroll
        for (int fi = 0; fi < 4; fi++) {
            int r = m_off + fi * 16 + l15;
            const float4* Ar = (const float4*)&As[w % 3][r * 32];
            int u0 = (quad * 2) ^ (r & 7);
            float4 v0 = Ar[u0];
            float4 v1 = Ar[u0 ^ 1];
            float f[8] = {v0.x, v0.y, v0.z, v0.w, v1.x, v1.y, v1.z, v1.w};
            half8 ah, al;
#pragma unroll
            for (int j = 0; j < 8; j++) {
                _Float16 h = (_Float16)f[j];
                ah[j] = h;
                al[j] = (_Float16)(f[j] - (float)h);
            }
#pragma unroll
            for (int fj = 0; fj < 4; fj++) {
                acc[fi][fj] = __builtin_amdgcn_mfma_f32_16x16x32_f16(
                    ah, BH[fj], acc[fi][fj], 0, 0, 0);
                acc[fi][fj] = __builtin_amdgcn_mfma_f32_16x16x32_f16(
                    ah, BL[fj], acc[fi][fj], 0, 0, 0);
                acc[fi][fj] = __builtin_amdgcn_mfma_f32_16x16x32_f16(
                    al, BH[fj], acc[fi][fj], 0, 0, 0);
            }
        }
    };

    // prologue: S0 B0 S1 B1 S2 in FIFO order
    stage(0);               __builtin_amdgcn_sched_barrier(0);
    loadb(0, bhA, blA);     __builtin_amdgcn_sched_barrier(0);
    stage(1);               __builtin_amdgcn_sched_barrier(0);
    loadb(1, bhB, blB);     __builtin_amdgcn_sched_barrier(0);
    stage(2);               __builtin_amdgcn_sched_barrier(0);

#pragma unroll
    for (int w = 0; w < 8; w++) {
        if (w <= 5)      asm volatile("s_waitcnt vmcnt(16)" ::: "memory");
        else if (w == 6) asm volatile("s_waitcnt vmcnt(12)" ::: "memory");
        else             asm volatile("s_waitcnt vmcnt(0)"  ::: "memory");
        __builtin_amdgcn_s_barrier();
        __builtin_amdgcn_sched_barrier(0);
        if (w & 1) compute(w, bhB, blB);
        else       compute(w, bhA, blA);
        __builtin_amdgcn_s_barrier();       // readers done before re-stage
        __builtin_amdgcn_sched_barrier(0);
        if (w + 2 <= 7) {
            if (w & 1) loadb(w + 2, bhB, blB);
            else       loadb(w + 2, bhA, blA);
            __builtin_amdgcn_sched_barrier(0);
        }
        if (w + 3 <= 7) {
            stage(w + 3);
            __builtin_amdgcn_sched_barrier(0);
        }
    }

    // epilogue: store COMPACT rows (tail rows >= vtotal are harmless writes)
#pragma unroll
    for (int fi = 0; fi < 4; fi++)
#pragma unroll
        for (int fj = 0; fj < 4; fj++)
#pragma unroll
            for (int q = 0; q < 4; q++) {
                int row = m0 + m_off + fi * 16 + quad * 4 + q;
                int col = n0 + n_off + fj * 16 + l15;
                G[(size_t)row * D + col] = acc[fi][fj][q];
            }
}

// ---------------------------------------------------------------------------
// K4: recurrence. One wave per doc; lane l owns dims 4l..4l+3 of s.
//     G is compact: row for (b,t) is offs[b]+t.  Depth-4 prefetch with
//     prefetch index clamped to dl-1 (always a valid compact row).
// ---------------------------------------------------------------------------
__device__ __forceinline__ float ftanh(float x)
{
    float e = __expf(2.0f * x);
    return 1.0f - 2.0f * __builtin_amdgcn_rcpf(e + 1.0f);
}

__global__ __launch_bounds__(256) void k4_recur(
    const float* __restrict__ sent, const float* __restrict__ G,
    const float* __restrict__ uw, const float* __restrict__ abs_w,
    const float* __restrict__ relw, const float* __restrict__ bias,
    const int* __restrict__ dls, const int* __restrict__ offs,
    float* __restrict__ out)
{
    int wave = threadIdx.x >> 6;
    int lane = threadIdx.x & 63;
    int b = blockIdx.x * 4 + wave;

    int dl = dls[b];
    float dlf = (float)dl;
    int base = offs[b];
    float bs = bias[0];

    const float4* h_ptr = (const float4*)(sent + (size_t)b * L * D) + lane;
    const float4* g_ptr = (const float4*)(G + (size_t)base * D) + lane;
    float4 uwv = ((const float4*)(uw + (size_t)b * D))[lane];

    float4 s = make_float4(0.f, 0.f, 0.f, 0.f);

    int c0 = 0 < dl - 1 ? 0 : dl - 1;
    int c1 = 1 < dl - 1 ? 1 : dl - 1;
    int c2 = 2 < dl - 1 ? 2 : dl - 1;
    int c3 = 3 < dl - 1 ? 3 : dl - 1;
    float4 h0 = h_ptr[(size_t)c0 * (D / 4)], g0 = g_ptr[(size_t)c0 * (D / 4)];
    float4 h1 = h_ptr[(size_t)c1 * (D / 4)], g1 = g_ptr[(size_t)c1 * (D / 4)];
    float4 h2 = h_ptr[(size_t)c2 * (D / 4)], g2 = g_ptr[(size_t)c2 * (D / 4)];
    float4 h3 = h_ptr[(size_t)c3 * (D / 4)], g3 = g_ptr[(size_t)c3 * (D / 4)];

    auto step = [&](float4& HH, float4& GG, int tt) {
        int tp = tt + 4; if (tp > dl - 1) tp = dl - 1;
        float4 hn = h_ptr[(size_t)tp * (D / 4)];
        float4 gn = g_ptr[(size_t)tp * (D / 4)];
        float4 ts;
        ts.x = ftanh(s.x); ts.y = ftanh(s.y);
        ts.z = ftanh(s.z); ts.w = ftanh(s.w);
        float r = HH.x * uwv.x + HH.y * uwv.y + HH.z * uwv.z + HH.w * uwv.w
                - (GG.x * ts.x + GG.y * ts.y + GG.z * ts.z + GG.w * ts.w);
        r += __shfl_xor(r, 32, 64);
        r += __shfl_xor(r, 16, 64);
        r += __shfl_xor(r, 8, 64);
        r += __shfl_xor(r, 4, 64);
        r += __shfl_xor(r, 2, 64);
        r += __shfl_xor(r, 1, 64);
        bool valid = tt < dl;
        int ta = valid ? tt : 0;
        int idx = (int)rintf((float)(tt + 1) * 9.0f / dlf);
        if (idx > 24) idx = 24;
        float pre = r + abs_w[ta] + relw[idx] + bs;
        float p = __builtin_amdgcn_rcpf(1.0f + __expf(-pre));
        float pm = valid ? p : 0.0f;
        s.x += pm * HH.x; s.y += pm * HH.y;
        s.z += pm * HH.z; s.w += pm * HH.w;
        if (valid && lane == 0) out[base + tt] = p;
        HH = hn; GG = gn;
    };

    int nsteps = (dl + 3) & ~3;
    for (int t = 0; t < nsteps; t += 4) {
        step(h0, g0, t);
        step(h1, g1, t + 1);
        step(h2, g2, t + 2);
        step(h3, g3, t + 3);
    }
}

// ---------------------------------------------------------------------------
extern "C" void kernel_launch(void* const* d_in, const int* in_sizes, int n_in,
                              void* d_out, int out_size, void* d_ws, size_t ws_size,
                              hipStream_t stream)
{
    const float* sent      = (const float*)d_in[0];
    const float* fc_w      = (const float*)d_in[1];
    const float* fc_b      = (const float*)d_in[2];
    const float* w_content = (const float*)d_in[3];
    const float* W_sal     = (const float*)d_in[4];
    const float* W_nov     = (const float*)d_in[5];
    const float* abs_embed = (const float*)d_in[6];
    const float* rel_embed = (const float*)d_in[7];
    const float* w_abs     = (const float*)d_in[8];
    const float* w_rel     = (const float*)d_in[9];
    const float* bias      = (const float*)d_in[10];
    const int*   dls       = (const int*)d_in[11];
    float* out = (float*)d_out;

    // workspace layout (bytes), all 16B-aligned
    char* ws = (char*)d_ws;
    int*      offs    = (int*)ws;                         // 2049 ints (8704 B)
    float*    abs_w   = (float*)(ws + 8704);              // 512 B
    float*    relw    = (float*)(ws + 9216);              // 512 B
    float*    docs    = (float*)(ws + 9728);              // 2 MiB
    float*    uw      = (float*)(ws + 9728 + (size_t)B * D * 4);          // 2 MiB
    _Float16* Wh      = (_Float16*)(ws + 9728 + 2 * (size_t)B * D * 4);   // 128 KiB
    _Float16* Wl      = (_Float16*)(ws + 9728 + 2 * (size_t)B * D * 4 + 131072);
    int*      row_map = (int*)(ws + 9728 + 2 * (size_t)B * D * 4 + 262144); // 800 KiB
    float*    G       = (float*)(ws + 9728 + 2 * (size_t)B * D * 4 + 262144
                                 + (size_t)NROWS * 4);    // up to 200 MiB (compact)

    hipLaunchKernelGGL(k0_precompute, dim3(1), dim3(256), 0, stream,
                       abs_embed, w_abs, rel_embed, w_rel, dls, abs_w, relw, offs);
    hipLaunchKernelGGL(k0c_rowmap, dim3(B), dim3(128), 0, stream,
                       dls, offs, row_map);
    hipLaunchKernelGGL(k0b_wt, dim3(D), dim3(D), 0, stream, W_nov, Wh, Wl);
    hipLaunchKernelGGL(k1_docavg, dim3(B / 4), dim3(256), 0, stream, sent, dls, docs);
    hipLaunchKernelGGL(k2_docrep, dim3(B / 8), dim3(256), 0, stream,
                       docs, fc_w, fc_b, W_sal, w_content, uw);
    hipLaunchKernelGGL(k3_mfma, dim3(2, (B * L) / 128), dim3(256), 0, stream,
                       sent, Wh, Wl, row_map, offs, G);
    hipLaunchKernelGGL(k4_recur, dim3(B / 4), dim3(256), 0, stream,
                       sent, G, uw, abs_w, relw, bias, dls, offs, out);
}

// Round 10
// 453.175 us; speedup vs baseline: 1.2808x; 1.0446x over previous
//
#include <hip/hip_runtime.h>
#include <hip/hip_bf16.h>
#include <math.h>

#define B 2048
#define L 100
#define D 256
#define NROWS (B * L)

typedef _Float16 half8 __attribute__((ext_vector_type(8)));
typedef __attribute__((ext_vector_type(4))) float f32x4;

// ---------------------------------------------------------------------------
// K0: abs_w[t] = abs_embed[t]·w_abs, relw[i] = rel_embed[i]·w_rel,
//     exclusive scan of doc_lens; offs[2048] = total valid rows.
// ---------------------------------------------------------------------------
__global__ __launch_bounds__(256) void k0_precompute(
    const float* __restrict__ abs_embed, const float* __restrict__ w_abs,
    const float* __restrict__ rel_embed, const float* __restrict__ w_rel,
    const int* __restrict__ dls,
    float* __restrict__ abs_w, float* __restrict__ relw, int* __restrict__ offs)
{
    int t = threadIdx.x;
    if (t < 100) {
        float s = 0.f;
        for (int j = 0; j < 50; j++) s += abs_embed[t * 50 + j] * w_abs[j];
        abs_w[t] = s;
    }
    if (t < 25) {
        float s = 0.f;
        for (int j = 0; j < 50; j++) s += rel_embed[t * 50 + j] * w_rel[j];
        relw[t] = s;
    }
    __shared__ int lds[256];
    int loc[8];
    int sum = 0;
    for (int k = 0; k < 8; k++) { loc[k] = sum; sum += dls[t * 8 + k]; }
    lds[t] = sum;
    __syncthreads();
    for (int off = 1; off < 256; off <<= 1) {
        int v = (t >= off) ? lds[t - off] : 0;
        __syncthreads();
        lds[t] += v;
        __syncthreads();
    }
    int base = (t > 0) ? lds[t - 1] : 0;
    for (int k = 0; k < 8; k++) offs[t * 8 + k] = base + loc[k];
    if (t == 255) offs[2048] = lds[255];          // vtotal
}

// ---------------------------------------------------------------------------
// K0c: row_map[offs[b]+t] = b*L+t for t < dl[b]  (compact valid-row index)
// ---------------------------------------------------------------------------
__global__ __launch_bounds__(128) void k0c_rowmap(
    const int* __restrict__ dls, const int* __restrict__ offs,
    int* __restrict__ row_map)
{
    int b = blockIdx.x, t = threadIdx.x;
    if (t < dls[b]) row_map[offs[b] + t] = b * L + t;
}

// ---------------------------------------------------------------------------
// K0b: split-fp16 transpose of W_nov: Wh/Wl are [N][K] fp16,
//      W = Wh + Wl with |err| <= 2^-22 rel.  (2 x 128 KB, L2-resident)
// ---------------------------------------------------------------------------
__global__ __launch_bounds__(256) void k0b_wt(
    const float* __restrict__ W, _Float16* __restrict__ Wh, _Float16* __restrict__ Wl)
{
    int n = blockIdx.x, k = threadIdx.x;
    float w = W[k * D + n];
    _Float16 hi = (_Float16)w;
    _Float16 lo = (_Float16)(w - (float)hi);
    Wh[n * D + k] = hi;
    Wl[n * D + k] = lo;
}

// ---------------------------------------------------------------------------
// K12: fused doc-average + doc-rep.
//     Phase 1: wave w averages docs g*8+2w, g*8+2w+1 straight into LDS
//     (no global docs round-trip).  Phase 2 = old k2: doc = tanh(fc(avg)),
//     uw = W_sal @ doc + w_content.
// ---------------------------------------------------------------------------
__global__ __launch_bounds__(256) void k12_docrep(
    const float* __restrict__ sent, const int* __restrict__ dls,
    const float* __restrict__ fc_w, const float* __restrict__ fc_b,
    const float* __restrict__ W_sal, const float* __restrict__ w_content,
    float* __restrict__ uw)
{
    __shared__ float sd[8][D];
    __shared__ float sdoc[8][D];
    int g = blockIdx.x;
    int i = threadIdx.x;
    int wave = i >> 6;
    int lane = i & 63;

    // ---- phase 1: averages for this block's 8 docs (2 per wave) ----
#pragma unroll
    for (int j = 0; j < 2; j++) {
        int dd = 2 * wave + j;
        int b = g * 8 + dd;
        int dl = dls[b];
        const float4* p = (const float4*)(sent + (size_t)b * L * D) + lane;
        float4 s = make_float4(0.f, 0.f, 0.f, 0.f);
        int t = 0;
        for (; t + 4 <= dl; t += 4) {
            float4 a = p[(size_t)t * (D / 4)];
            float4 c = p[(size_t)(t + 1) * (D / 4)];
            float4 e = p[(size_t)(t + 2) * (D / 4)];
            float4 f = p[(size_t)(t + 3) * (D / 4)];
            s.x += (a.x + c.x) + (e.x + f.x);
            s.y += (a.y + c.y) + (e.y + f.y);
            s.z += (a.z + c.z) + (e.z + f.z);
            s.w += (a.w + c.w) + (e.w + f.w);
        }
        for (; t < dl; t++) {
            float4 a = p[(size_t)t * (D / 4)];
            s.x += a.x; s.y += a.y; s.z += a.z; s.w += a.w;
        }
        float inv = 1.0f / (float)dl;
        float4 r = make_float4(s.x * inv, s.y * inv, s.z * inv, s.w * inv);
        ((float4*)sd[dd])[lane] = r;
    }
    __syncthreads();

    // ---- phase 2: doc rep + uw (identical arithmetic to old k2) ----
    float acc[8];
    float fb = fc_b[i];
#pragma unroll
    for (int dd = 0; dd < 8; dd++) acc[dd] = fb;
    const float4* wr = (const float4*)(fc_w + (size_t)i * D);
    for (int j = 0; j < D / 4; j++) {
        float4 w = wr[j];
#pragma unroll
        for (int dd = 0; dd < 8; dd++) {
            float4 v = ((const float4*)sd[dd])[j];
            acc[dd] += w.x * v.x + w.y * v.y + w.z * v.z + w.w * v.w;
        }
    }
#pragma unroll
    for (int dd = 0; dd < 8; dd++) sdoc[dd][i] = tanhf(acc[dd]);
    __syncthreads();

    float acc2[8];
#pragma unroll
    for (int dd = 0; dd < 8; dd++) acc2[dd] = 0.f;
    const float4* wsr = (const float4*)(W_sal + (size_t)i * D);
    for (int j = 0; j < D / 4; j++) {
        float4 w = wsr[j];
#pragma unroll
        for (int dd = 0; dd < 8; dd++) {
            float4 v = ((const float4*)sdoc[dd])[j];
            acc2[dd] += w.x * v.x + w.y * v.y + w.z * v.z + w.w * v.w;
        }
    }
    float wc = w_content[i];
#pragma unroll
    for (int dd = 0; dd < 8; dd++)
        uw[(size_t)(g * 8 + dd) * D + i] = acc2[dd] + wc;
}

// ---------------------------------------------------------------------------
// K3: compact-row G = sent[valid rows] @ W_nov, split-fp16 MFMA.
//     (round-9 winner, unchanged)
// ---------------------------------------------------------------------------
__global__ __launch_bounds__(256, 3) void k3_mfma(
    const float* __restrict__ A, const _Float16* __restrict__ Wh,
    const _Float16* __restrict__ Wl, const int* __restrict__ row_map,
    const int* __restrict__ offs, float* __restrict__ G)
{
    __shared__ __align__(16) float As[3][128 * 32];   // 3 x 16 KB

    int vtotal = offs[2048];
    int m0 = blockIdx.y * 128;
    if (m0 >= vtotal) return;                 // uniform early-exit (tail tiles)

    int tid = threadIdx.x;
    int lane = tid & 63;
    int wv = tid >> 6;
    int n0 = blockIdx.x * 128;                // gridDim.x = 2
    int m_off = (wv & 1) * 64;
    int n_off = (wv >> 1) * 64;
    int quad = lane >> 4;
    int l15 = lane & 15;

    // per-thread A gather bases: granule g = i*256+tid -> row r = g>>3
    const float* srcb[4];
#pragma unroll
    for (int i = 0; i < 4; i++) {
        int flat = i * 256 + tid;
        int r = flat >> 3, u = flat & 7;
        int us = u ^ (r & 7);
        unsigned rb = (unsigned)row_map[m0 + r];
        if (rb > (unsigned)(NROWS - 1)) rb = 0;       // clamp poison in tail
        srcb[i] = A + (size_t)rb * D + us * 4;
    }

    f32x4 acc[4][4];
#pragma unroll
    for (int fi = 0; fi < 4; fi++)
#pragma unroll
        for (int fj = 0; fj < 4; fj++) acc[fi][fj] = (f32x4){0.f, 0.f, 0.f, 0.f};

    half8 bhA[4], blA[4], bhB[4], blB[4];

    auto stage = [&](int w) {
#pragma unroll
        for (int i = 0; i < 4; i++) {
            const float* src = srcb[i] + w * 32;
            float* dst = &As[w % 3][(i * 256 + wv * 64) * 4];
            __builtin_amdgcn_global_load_lds(
                (const __attribute__((address_space(1))) void*)src,
                (__attribute__((address_space(3))) void*)dst, 16, 0, 0);
        }
    };

    auto loadb = [&](int w, half8* BH, half8* BL) {
#pragma unroll
        for (int fj = 0; fj < 4; fj++) {
            size_t wo = (size_t)(n0 + n_off + fj * 16 + l15) * D
                      + w * 32 + quad * 8;
            BH[fj] = *(const half8*)(Wh + wo);
            BL[fj] = *(const half8*)(Wl + wo);
        }
    };

    auto compute = [&](int w, const half8* BH, const half8* BL) {
#pragma unroll
        for (int fi = 0; fi < 4; fi++) {
            int r = m_off + fi * 16 + l15;
            const float4* Ar = (const float4*)&As[w % 3][r * 32];
            int u0 = (quad * 2) ^ (r & 7);
            float4 v0 = Ar[u0];
            float4 v1 = Ar[u0 ^ 1];
            float f[8] = {v0.x, v0.y, v0.z, v0.w, v1.x, v1.y, v1.z, v1.w};
            half8 ah, al;
#pragma unroll
            for (int j = 0; j < 8; j++) {
                _Float16 h = (_Float16)f[j];
                ah[j] = h;
                al[j] = (_Float16)(f[j] - (float)h);
            }
#pragma unroll
            for (int fj = 0; fj < 4; fj++) {
                acc[fi][fj] = __builtin_amdgcn_mfma_f32_16x16x32_f16(
                    ah, BH[fj], acc[fi][fj], 0, 0, 0);
                acc[fi][fj] = __builtin_amdgcn_mfma_f32_16x16x32_f16(
                    ah, BL[fj], acc[fi][fj], 0, 0, 0);
                acc[fi][fj] = __builtin_amdgcn_mfma_f32_16x16x32_f16(
                    al, BH[fj], acc[fi][fj], 0, 0, 0);
            }
        }
    };

    // prologue: S0 B0 S1 B1 S2 in FIFO order
    stage(0);               __builtin_amdgcn_sched_barrier(0);
    loadb(0, bhA, blA);     __builtin_amdgcn_sched_barrier(0);
    stage(1);               __builtin_amdgcn_sched_barrier(0);
    loadb(1, bhB, blB);     __builtin_amdgcn_sched_barrier(0);
    stage(2);               __builtin_amdgcn_sched_barrier(0);

#pragma unroll
    for (int w = 0; w < 8; w++) {
        if (w <= 5)      asm volatile("s_waitcnt vmcnt(16)" ::: "memory");
        else if (w == 6) asm volatile("s_waitcnt vmcnt(12)" ::: "memory");
        else             asm volatile("s_waitcnt vmcnt(0)"  ::: "memory");
        __builtin_amdgcn_s_barrier();
        __builtin_amdgcn_sched_barrier(0);
        if (w & 1) compute(w, bhB, blB);
        else       compute(w, bhA, blA);
        __builtin_amdgcn_s_barrier();       // readers done before re-stage
        __builtin_amdgcn_sched_barrier(0);
        if (w + 2 <= 7) {
            if (w & 1) loadb(w + 2, bhB, blB);
            else       loadb(w + 2, bhA, blA);
            __builtin_amdgcn_sched_barrier(0);
        }
        if (w + 3 <= 7) {
            stage(w + 3);
            __builtin_amdgcn_sched_barrier(0);
        }
    }

    // epilogue: store COMPACT rows (tail rows >= vtotal are harmless writes)
#pragma unroll
    for (int fi = 0; fi < 4; fi++)
#pragma unroll
        for (int fj = 0; fj < 4; fj++)
#pragma unroll
            for (int q = 0; q < 4; q++) {
                int row = m0 + m_off + fi * 16 + quad * 4 + q;
                int col = n0 + n_off + fj * 16 + l15;
                G[(size_t)row * D + col] = acc[fi][fj][q];
            }
}

// ---------------------------------------------------------------------------
// K4: recurrence. One wave per doc; lane l owns dims 4l..4l+3 of s.
//     G compact; depth-4 prefetch.  Wave reduction via DPP
//     (4x row_shr + bcast15 + bcast31, ~25 cyc) instead of 6x ds_bpermute
//     shuffles (~200+ cyc) -- the reduce is on the serial critical path.
// ---------------------------------------------------------------------------
__device__ __forceinline__ float ftanh(float x)
{
    float e = __expf(2.0f * x);
    return 1.0f - 2.0f * __builtin_amdgcn_rcpf(e + 1.0f);
}

__device__ __forceinline__ float wave_sum64(float v)
{
    // AMD canonical wave64 sum; total lands in lane 63, then readlane.
    // update_dpp(old=0,...) -> invalid lanes contribute 0.
    v += __int_as_float(__builtin_amdgcn_update_dpp(
            0, __float_as_int(v), 0x111, 0xf, 0xf, false));  // row_shr:1
    v += __int_as_float(__builtin_amdgcn_update_dpp(
            0, __float_as_int(v), 0x112, 0xf, 0xf, false));  // row_shr:2
    v += __int_as_float(__builtin_amdgcn_update_dpp(
            0, __float_as_int(v), 0x114, 0xf, 0xf, false));  // row_shr:4
    v += __int_as_float(__builtin_amdgcn_update_dpp(
            0, __float_as_int(v), 0x118, 0xf, 0xf, false));  // row_shr:8
    v += __int_as_float(__builtin_amdgcn_update_dpp(
            0, __float_as_int(v), 0x142, 0xf, 0xf, false));  // row_bcast:15
    v += __int_as_float(__builtin_amdgcn_update_dpp(
            0, __float_as_int(v), 0x143, 0xf, 0xf, false));  // row_bcast:31
    return __int_as_float(__builtin_amdgcn_readlane(__float_as_int(v), 63));
}

__global__ __launch_bounds__(256) void k4_recur(
    const float* __restrict__ sent, const float* __restrict__ G,
    const float* __restrict__ uw, const float* __restrict__ abs_w,
    const float* __restrict__ relw, const float* __restrict__ bias,
    const int* __restrict__ dls, const int* __restrict__ offs,
    float* __restrict__ out)
{
    int wave = threadIdx.x >> 6;
    int lane = threadIdx.x & 63;
    int b = blockIdx.x * 4 + wave;

    int dl = dls[b];
    float dlf = (float)dl;
    int base = offs[b];
    float bs = bias[0];

    const float4* h_ptr = (const float4*)(sent + (size_t)b * L * D) + lane;
    const float4* g_ptr = (const float4*)(G + (size_t)base * D) + lane;
    float4 uwv = ((const float4*)(uw + (size_t)b * D))[lane];

    float4 s = make_float4(0.f, 0.f, 0.f, 0.f);

    int c0 = 0 < dl - 1 ? 0 : dl - 1;
    int c1 = 1 < dl - 1 ? 1 : dl - 1;
    int c2 = 2 < dl - 1 ? 2 : dl - 1;
    int c3 = 3 < dl - 1 ? 3 : dl - 1;
    float4 h0 = h_ptr[(size_t)c0 * (D / 4)], g0 = g_ptr[(size_t)c0 * (D / 4)];
    float4 h1 = h_ptr[(size_t)c1 * (D / 4)], g1 = g_ptr[(size_t)c1 * (D / 4)];
    float4 h2 = h_ptr[(size_t)c2 * (D / 4)], g2 = g_ptr[(size_t)c2 * (D / 4)];
    float4 h3 = h_ptr[(size_t)c3 * (D / 4)], g3 = g_ptr[(size_t)c3 * (D / 4)];

    auto step = [&](float4& HH, float4& GG, int tt) {
        int tp = tt + 4; if (tp > dl - 1) tp = dl - 1;
        float4 hn = h_ptr[(size_t)tp * (D / 4)];
        float4 gn = g_ptr[(size_t)tp * (D / 4)];
        float4 ts;
        ts.x = ftanh(s.x); ts.y = ftanh(s.y);
        ts.z = ftanh(s.z); ts.w = ftanh(s.w);
        float rp = HH.x * uwv.x + HH.y * uwv.y + HH.z * uwv.z + HH.w * uwv.w
                 - (GG.x * ts.x + GG.y * ts.y + GG.z * ts.z + GG.w * ts.w);
        float r = wave_sum64(rp);
        bool valid = tt < dl;
        int ta = valid ? tt : 0;
        int idx = (int)rintf((float)(tt + 1) * 9.0f / dlf);
        if (idx > 24) idx = 24;
        float pre = r + abs_w[ta] + relw[idx] + bs;
        float p = __builtin_amdgcn_rcpf(1.0f + __expf(-pre));
        float pm = valid ? p : 0.0f;
        s.x += pm * HH.x; s.y += pm * HH.y;
        s.z += pm * HH.z; s.w += pm * HH.w;
        if (valid && lane == 0) out[base + tt] = p;
        HH = hn; GG = gn;
    };

    int nsteps = (dl + 3) & ~3;
    for (int t = 0; t < nsteps; t += 4) {
        step(h0, g0, t);
        step(h1, g1, t + 1);
        step(h2, g2, t + 2);
        step(h3, g3, t + 3);
    }
}

// ---------------------------------------------------------------------------
extern "C" void kernel_launch(void* const* d_in, const int* in_sizes, int n_in,
                              void* d_out, int out_size, void* d_ws, size_t ws_size,
                              hipStream_t stream)
{
    const float* sent      = (const float*)d_in[0];
    const float* fc_w      = (const float*)d_in[1];
    const float* fc_b      = (const float*)d_in[2];
    const float* w_content = (const float*)d_in[3];
    const float* W_sal     = (const float*)d_in[4];
    const float* W_nov     = (const float*)d_in[5];
    const float* abs_embed = (const float*)d_in[6];
    const float* rel_embed = (const float*)d_in[7];
    const float* w_abs     = (const float*)d_in[8];
    const float* w_rel     = (const float*)d_in[9];
    const float* bias      = (const float*)d_in[10];
    const int*   dls       = (const int*)d_in[11];
    float* out = (float*)d_out;

    // workspace layout (bytes), all 16B-aligned
    char* ws = (char*)d_ws;
    int*      offs    = (int*)ws;                         // 2049 ints (8704 B)
    float*    abs_w   = (float*)(ws + 8704);              // 512 B
    float*    relw    = (float*)(ws + 9216);              // 512 B
    float*    uw      = (float*)(ws + 9728);              // 2 MiB
    _Float16* Wh      = (_Float16*)(ws + 9728 + (size_t)B * D * 4);   // 128 KiB
    _Float16* Wl      = (_Float16*)(ws + 9728 + (size_t)B * D * 4 + 131072);
    int*      row_map = (int*)(ws + 9728 + (size_t)B * D * 4 + 262144); // 800 KiB
    float*    G       = (float*)(ws + 9728 + (size_t)B * D * 4 + 262144
                                 + (size_t)NROWS * 4);    // up to 200 MiB (compact)

    hipLaunchKernelGGL(k0_precompute, dim3(1), dim3(256), 0, stream,
                       abs_embed, w_abs, rel_embed, w_rel, dls, abs_w, relw, offs);
    hipLaunchKernelGGL(k0c_rowmap, dim3(B), dim3(128), 0, stream,
                       dls, offs, row_map);
    hipLaunchKernelGGL(k0b_wt, dim3(D), dim3(D), 0, stream, W_nov, Wh, Wl);
    hipLaunchKernelGGL(k12_docrep, dim3(B / 8), dim3(256), 0, stream,
                       sent, dls, fc_w, fc_b, W_sal, w_content, uw);
    hipLaunchKernelGGL(k3_mfma, dim3(2, (B * L) / 128), dim3(256), 0, stream,
                       sent, Wh, Wl, row_map, offs, G);
    hipLaunchKernelGGL(k4_recur, dim3(B / 4), dim3(256), 0, stream,
                       sent, G, uw, abs_w, relw, bias, dls, offs, out);
}